// Round 1
// baseline (378.846 us; speedup 1.0000x reference)
//
#include <hip/hip_runtime.h>
#include <stdint.h>

typedef short short8 __attribute__((ext_vector_type(8)));
typedef float f32x4 __attribute__((ext_vector_type(4)));

__device__ __forceinline__ unsigned short f2bf(float f) {
    union { float f; uint32_t u; } v; v.f = f;
    uint32_t u = v.u;
    u += 0x7FFFu + ((u >> 16) & 1u);   // round-to-nearest-even
    return (unsigned short)(u >> 16);
}

// ---------------- fp32 -> bf16 elementwise convert (vectorized) ----------------
__global__ void k_f32_to_bf16(const float* __restrict__ in, unsigned short* __restrict__ out, int n4) {
    int i = blockIdx.x * blockDim.x + threadIdx.x;
    if (i < n4) {
        float4 f = ((const float4*)in)[i];
        ushort4 o;
        o.x = f2bf(f.x); o.y = f2bf(f.y); o.z = f2bf(f.z); o.w = f2bf(f.w);
        ((ushort4*)out)[i] = o;
    }
}

// ---------------- fp32 [R][Cc] -> bf16 transposed [Cc][R] ----------------
__global__ void k_transpose_f32_bf16(const float* __restrict__ in, unsigned short* __restrict__ out,
                                     int R, int Cc) {
    __shared__ float tile[32][33];
    int c0 = blockIdx.x * 32, r0 = blockIdx.y * 32;
    int tr = threadIdx.x / 32, c = threadIdx.x % 32;
#pragma unroll
    for (int rr = tr; rr < 32; rr += 8)
        tile[rr][c] = in[(size_t)(r0 + rr) * Cc + c0 + c];
    __syncthreads();
#pragma unroll
    for (int rr = tr; rr < 32; rr += 8)
        out[(size_t)(c0 + rr) * R + r0 + c] = f2bf(tile[c][rr]);
}

// ---------------- bf16 GEMM, C = A[M][K] * BT[N][K]^T + bias ----------------
// 128x128 tile, BK=32, 4 waves (2x2), each wave 64x64 = 4x4 frags of 16x16x32 MFMA.
template<bool F32OUT>
__global__ __launch_bounds__(256, 2)
void k_gemm_bt(const unsigned short* __restrict__ A, const unsigned short* __restrict__ BT,
               const float* __restrict__ bias, void* __restrict__ Cout,
               int M, int N, int K) {
    __shared__ unsigned short As[128][40];
    __shared__ unsigned short Bs[128][40];
    const int m0 = blockIdx.y * 128, n0 = blockIdx.x * 128;
    const int t = threadIdx.x;
    const int w = t >> 6, l = t & 63;
    const int wm = (w >> 1) * 64, wn = (w & 1) * 64;
    const int lr = l & 15, lg = l >> 4;
    const int sr0 = t >> 2, sc0 = (t & 3) * 8;

    f32x4 acc[4][4];
#pragma unroll
    for (int i = 0; i < 4; ++i)
#pragma unroll
        for (int j = 0; j < 4; ++j)
#pragma unroll
            for (int r = 0; r < 4; ++r) acc[i][j][r] = 0.0f;

    for (int k0 = 0; k0 < K; k0 += 32) {
        uint4 ra[2], rb[2];
#pragma unroll
        for (int i = 0; i < 2; ++i) {
            int row = sr0 + i * 64;
            ra[i] = *(const uint4*)&A [(size_t)(m0 + row) * K + k0 + sc0];
            rb[i] = *(const uint4*)&BT[(size_t)(n0 + row) * K + k0 + sc0];
        }
        __syncthreads();
#pragma unroll
        for (int i = 0; i < 2; ++i) {
            int row = sr0 + i * 64;
            *(uint4*)&As[row][sc0] = ra[i];
            *(uint4*)&Bs[row][sc0] = rb[i];
        }
        __syncthreads();
        short8 af[4], bfr[4];
#pragma unroll
        for (int f = 0; f < 4; ++f) {
            af [f] = *(const short8*)&As[wm + f * 16 + lr][lg * 8];
            bfr[f] = *(const short8*)&Bs[wn + f * 16 + lr][lg * 8];
        }
#pragma unroll
        for (int mf = 0; mf < 4; ++mf)
#pragma unroll
            for (int nf = 0; nf < 4; ++nf)
                acc[mf][nf] = __builtin_amdgcn_mfma_f32_16x16x32_bf16(af[mf], bfr[nf], acc[mf][nf], 0, 0, 0);
    }

#pragma unroll
    for (int mf = 0; mf < 4; ++mf)
#pragma unroll
        for (int nf = 0; nf < 4; ++nf) {
            int n = n0 + wn + nf * 16 + lr;
            int mbase = m0 + wm + mf * 16 + lg * 4;
            float bv = bias[n];
#pragma unroll
            for (int r = 0; r < 4; ++r) {
                float v = acc[mf][nf][r] + bv;
                if (F32OUT) ((float*)Cout)[(size_t)(mbase + r) * N + n] = v;
                else ((unsigned short*)Cout)[(size_t)(mbase + r) * N + n] = f2bf(v);
            }
        }
}

// ---------------- causal flash attention ----------------
// qkv bf16 [B*T][3C]; y bf16 [B*T][C]. Block: 64 q-rows, 4 waves x 16 rows. KV tile = 32.
__global__ __launch_bounds__(256, 2)
void k_attn(const unsigned short* __restrict__ qkv, unsigned short* __restrict__ y) {
    __shared__ unsigned short Qs[64][72];
    __shared__ unsigned short Ks[32][72];
    __shared__ unsigned short Vt[64][40];   // V^T: [d][k]
    __shared__ unsigned short Ps[4][16][40];
    const int qi = blockIdx.x;            // q-tile
    const int bh = blockIdx.y;            // b*12+h
    const int b = bh / 12, h = bh % 12;
    const int q0 = qi * 64;
    const int t = threadIdx.x, w = t >> 6, l = t & 63, lr = l & 15, lg = l >> 4;

    const unsigned short* qbase = qkv + (size_t)(b * 1024) * 2304 + h * 64;
    const unsigned short* kbase = qbase + 768;
    const unsigned short* vbase = qbase + 1536;

    // stage Q (64 x 64)
#pragma unroll
    for (int i = 0; i < 2; ++i) {
        int idx = t + 256 * i;
        int row = idx >> 3, c8 = (idx & 7) * 8;
        *(uint4*)&Qs[row][c8] = *(const uint4*)&qbase[(size_t)(q0 + row) * 2304 + c8];
    }
    __syncthreads();
    short8 qf0 = *(const short8*)&Qs[w * 16 + lr][lg * 8];
    short8 qf1 = *(const short8*)&Qs[w * 16 + lr][32 + lg * 8];

    float m_st[4], l_st[4];
    f32x4 o_acc[4];
#pragma unroll
    for (int r = 0; r < 4; ++r) { m_st[r] = -1e30f; l_st[r] = 0.0f; }
#pragma unroll
    for (int df = 0; df < 4; ++df)
#pragma unroll
        for (int r = 0; r < 4; ++r) o_acc[df][r] = 0.0f;

    const int nkt = q0 / 32 + 2;
    const int qwmax = q0 + w * 16 + 15;
    const int srow = t >> 3, sc8 = (t & 7) * 8;

    for (int kti = 0; kti < nkt; ++kti) {
        const int kt = kti * 32;
        uint4 kv = *(const uint4*)&kbase[(size_t)(kt + srow) * 2304 + sc8];
        uint4 vv = *(const uint4*)&vbase[(size_t)(kt + srow) * 2304 + sc8];
        __syncthreads();   // previous tile's compute done with Ks/Vt
        *(uint4*)&Ks[srow][sc8] = kv;
        {
            unsigned short tmp[8];
            *(uint4*)tmp = vv;
#pragma unroll
            for (int j = 0; j < 8; ++j) Vt[sc8 + j][srow] = tmp[j];
        }
        __syncthreads();

        if (kt <= qwmax) {
            f32x4 s[2];
#pragma unroll
            for (int nf = 0; nf < 2; ++nf) {
                short8 kf0 = *(const short8*)&Ks[nf * 16 + lr][lg * 8];
                short8 kf1 = *(const short8*)&Ks[nf * 16 + lr][32 + lg * 8];
                f32x4 z;
#pragma unroll
                for (int r = 0; r < 4; ++r) z[r] = 0.0f;
                z = __builtin_amdgcn_mfma_f32_16x16x32_bf16(qf0, kf0, z, 0, 0, 0);
                z = __builtin_amdgcn_mfma_f32_16x16x32_bf16(qf1, kf1, z, 0, 0, 0);
                s[nf] = z;
            }
            float sv[2][4];
#pragma unroll
            for (int nf = 0; nf < 2; ++nf) {
                int col = kt + nf * 16 + lr;
#pragma unroll
                for (int r = 0; r < 4; ++r) {
                    int row = q0 + w * 16 + lg * 4 + r;
                    float xv = s[nf][r] * 0.125f;
                    sv[nf][r] = (col <= row) ? xv : -1e30f;
                }
            }
            float pv[2][4];
#pragma unroll
            for (int r = 0; r < 4; ++r) {
                float mx = fmaxf(sv[0][r], sv[1][r]);
#pragma unroll
                for (int d = 1; d < 16; d <<= 1) mx = fmaxf(mx, __shfl_xor(mx, d));
                float mn = fmaxf(m_st[r], mx);
                float alpha = __expf(m_st[r] - mn);
                m_st[r] = mn;
                pv[0][r] = __expf(sv[0][r] - mn);
                pv[1][r] = __expf(sv[1][r] - mn);
                float s_ = pv[0][r] + pv[1][r];
#pragma unroll
                for (int d = 1; d < 16; d <<= 1) s_ += __shfl_xor(s_, d);
                l_st[r] = l_st[r] * alpha + s_;
#pragma unroll
                for (int df = 0; df < 4; ++df) o_acc[df][r] *= alpha;
            }
            // P -> LDS (per-wave buffer) to get MFMA A-fragment layout
#pragma unroll
            for (int nf = 0; nf < 2; ++nf)
#pragma unroll
                for (int r = 0; r < 4; ++r)
                    Ps[w][lg * 4 + r][nf * 16 + lr] = f2bf(pv[nf][r]);
            asm volatile("s_waitcnt lgkmcnt(0)" ::: "memory");
            short8 pf = *(const short8*)&Ps[w][lr][lg * 8];
#pragma unroll
            for (int df = 0; df < 4; ++df) {
                short8 vf = *(const short8*)&Vt[df * 16 + lr][lg * 8];
                o_acc[df] = __builtin_amdgcn_mfma_f32_16x16x32_bf16(pf, vf, o_acc[df], 0, 0, 0);
            }
        }
    }

#pragma unroll
    for (int df = 0; df < 4; ++df)
#pragma unroll
        for (int r = 0; r < 4; ++r) {
            int row = q0 + w * 16 + lg * 4 + r;
            float ov = o_acc[df][r] / l_st[r];
            y[((size_t)(b * 1024) + row) * 768 + h * 64 + df * 16 + lr] = f2bf(ov);
        }
}

extern "C" void kernel_launch(void* const* d_in, const int* in_sizes, int n_in,
                              void* d_out, int out_size, void* d_ws, size_t ws_size,
                              hipStream_t stream) {
    const float* x  = (const float*)d_in[0];
    const float* Wa = (const float*)d_in[1];
    const float* ba = (const float*)d_in[2];
    const float* Wp = (const float*)d_in[3];
    const float* bp = (const float*)d_in[4];
    float* out = (float*)d_out;

    char* ws = (char*)d_ws;
    unsigned short* qkv = (unsigned short*)ws;                          // 8192*2304*2 = 37,748,736
    unsigned short* xb  = (unsigned short*)(ws + 37748736);             // 8192*768*2  = 12,582,912
    unsigned short* WaT = (unsigned short*)(ws + 37748736 + 12582912);  // 2304*768*2  =  3,538,944
    unsigned short* y   = xb;    // reuse: xb dead after gemm1
    unsigned short* WpT = WaT;   // reuse: WaT dead after gemm1

    // 1) x fp32 -> bf16
    k_f32_to_bf16<<<6144, 256, 0, stream>>>(x, xb, 1572864);
    // 2) W_attn [768][2304] -> bf16 [2304][768]
    k_transpose_f32_bf16<<<dim3(72, 24), 256, 0, stream>>>(Wa, WaT, 768, 2304);
    // 3) qkv = xb @ WaT^T + b_attn   (bf16 out)
    k_gemm_bt<false><<<dim3(18, 64), 256, 0, stream>>>(xb, WaT, ba, qkv, 8192, 2304, 768);
    // 4) causal flash attention -> y (bf16), overwrites xb region
    k_attn<<<dim3(16, 96), 256, 0, stream>>>(qkv, y);
    // 5) W_proj [768][768] -> bf16 [768][768] transposed
    k_transpose_f32_bf16<<<dim3(24, 24), 256, 0, stream>>>(Wp, WpT, 768, 768);
    // 6) out = y @ WpT^T + b_proj    (fp32 out)
    k_gemm_bt<true><<<dim3(6, 64), 256, 0, stream>>>(y, WpT, bp, out, 8192, 768, 768);
}

// Round 2
// 229.933 us; speedup vs baseline: 1.6476x; 1.6476x over previous
//
#include <hip/hip_runtime.h>
#include <stdint.h>

typedef short short8 __attribute__((ext_vector_type(8)));
typedef float f32x4 __attribute__((ext_vector_type(4)));

__device__ __forceinline__ unsigned short f2bf(float f) {
    union { float f; uint32_t u; } v; v.f = f;
    uint32_t u = v.u;
    u += 0x7FFFu + ((u >> 16) & 1u);   // round-to-nearest-even
    return (unsigned short)(u >> 16);
}

__device__ __forceinline__ void gload_lds16(const void* g, void* l) {
    __builtin_amdgcn_global_load_lds(
        (const __attribute__((address_space(1))) void*)g,
        (__attribute__((address_space(3))) void*)l, 16, 0, 0);
}

// ---------------- fp32 -> bf16 elementwise convert (vectorized) ----------------
__global__ void k_f32_to_bf16(const float* __restrict__ in, unsigned short* __restrict__ out, int n4) {
    int i = blockIdx.x * blockDim.x + threadIdx.x;
    if (i < n4) {
        float4 f = ((const float4*)in)[i];
        ushort4 o;
        o.x = f2bf(f.x); o.y = f2bf(f.y); o.z = f2bf(f.z); o.w = f2bf(f.w);
        ((ushort4*)out)[i] = o;
    }
}

// ---------------- fp32 [R][Cc] -> bf16 transposed [Cc][R] ----------------
__global__ void k_transpose_f32_bf16(const float* __restrict__ in, unsigned short* __restrict__ out,
                                     int R, int Cc) {
    __shared__ float tile[32][33];
    int c0 = blockIdx.x * 32, r0 = blockIdx.y * 32;
    int tr = threadIdx.x / 32, c = threadIdx.x % 32;
#pragma unroll
    for (int rr = tr; rr < 32; rr += 8)
        tile[rr][c] = in[(size_t)(r0 + rr) * Cc + c0 + c];
    __syncthreads();
#pragma unroll
    for (int rr = tr; rr < 32; rr += 8)
        out[(size_t)(c0 + rr) * R + r0 + c] = f2bf(tile[c][rr]);
}

// ---------------- V head-transpose: qkv bf16 [B*T][2304] -> vt [96][64][1024] ----------------
__global__ void k_vt(const unsigned short* __restrict__ qkv, unsigned short* __restrict__ vt) {
    __shared__ unsigned short tile[32][34];
    const int k0 = blockIdx.x * 32, d0 = blockIdx.y * 32, bh = blockIdx.z;
    const int b = bh / 12, h = bh % 12;
    const unsigned short* src = qkv + (size_t)b * 1024 * 2304 + 1536 + h * 64;
    unsigned short* dst = vt + (size_t)bh * 64 * 1024;
    const int tr = threadIdx.x >> 5, c = threadIdx.x & 31;
#pragma unroll
    for (int rr = tr; rr < 32; rr += 8)
        tile[rr][c] = src[(size_t)(k0 + rr) * 2304 + d0 + c];
    __syncthreads();
#pragma unroll
    for (int rr = tr; rr < 32; rr += 8)
        dst[(size_t)(d0 + rr) * 1024 + k0 + c] = tile[c][rr];
}

// ---------------- bf16 GEMM (m97 structure): C = A[M][K] * BT[N][K]^T + bias ----------------
// 128x128 tile, BK=32, linear LDS, global_load_lds width=16, 2 barriers/K-step.
template<bool F32OUT>
__global__ __launch_bounds__(256, 2)
void k_gemm_bt(const unsigned short* __restrict__ A, const unsigned short* __restrict__ BT,
               const float* __restrict__ bias, void* __restrict__ Cout,
               int M, int N, int K) {
    __shared__ unsigned short As[128][32];
    __shared__ unsigned short Bs[128][32];
    const int m0 = blockIdx.y * 128, n0 = blockIdx.x * 128;
    const int t = threadIdx.x;
    const int w = t >> 6, l = t & 63;
    const int wm = (w >> 1) * 64, wn = (w & 1) * 64;
    const int lr = l & 15, lg = l >> 4;
    // staging: wave w covers LDS rows w*32..w*32+31 in two 1KB chunks (lane -> base + l*16)
    const int srow = w * 32 + (l >> 2);
    const int scol = (l & 3) * 8;
    const unsigned short* pa = &A [(size_t)(m0 + srow) * K + scol];
    const unsigned short* pb = &BT[(size_t)(n0 + srow) * K + scol];

    f32x4 acc[4][4];
#pragma unroll
    for (int i = 0; i < 4; ++i)
#pragma unroll
        for (int j = 0; j < 4; ++j)
#pragma unroll
            for (int r = 0; r < 4; ++r) acc[i][j][r] = 0.0f;

    for (int k0 = 0; k0 < K; k0 += 32) {
        __syncthreads();   // all waves done reading previous tile
        gload_lds16(pa + k0,                   &As[w * 32][0]);
        gload_lds16(pa + (size_t)16 * K + k0,  &As[w * 32 + 16][0]);
        gload_lds16(pb + k0,                   &Bs[w * 32][0]);
        gload_lds16(pb + (size_t)16 * K + k0,  &Bs[w * 32 + 16][0]);
        __syncthreads();   // drains vmcnt for global_load_lds
        short8 af[4], bfv[4];
#pragma unroll
        for (int f = 0; f < 4; ++f) {
            af [f] = *(const short8*)&As[wm + f * 16 + lr][lg * 8];
            bfv[f] = *(const short8*)&Bs[wn + f * 16 + lr][lg * 8];
        }
#pragma unroll
        for (int mf = 0; mf < 4; ++mf)
#pragma unroll
            for (int nf = 0; nf < 4; ++nf)
                acc[mf][nf] = __builtin_amdgcn_mfma_f32_16x16x32_bf16(af[mf], bfv[nf], acc[mf][nf], 0, 0, 0);
    }

#pragma unroll
    for (int mf = 0; mf < 4; ++mf)
#pragma unroll
        for (int nf = 0; nf < 4; ++nf) {
            int n = n0 + wn + nf * 16 + lr;
            int mbase = m0 + wm + mf * 16 + lg * 4;
            float bv = bias[n];
#pragma unroll
            for (int r = 0; r < 4; ++r) {
                float v = acc[mf][nf][r] + bv;
                if (F32OUT) ((float*)Cout)[(size_t)(mbase + r) * N + n] = v;
                else ((unsigned short*)Cout)[(size_t)(mbase + r) * N + n] = f2bf(v);
            }
        }
}

// ---------------- causal flash attention: barrier-free, L2-direct K/V ----------------
// Each wave owns 16 q-rows. KVBLK=64. Q/K/V^T fragments loaded straight from global (L2-resident
// per XCD via swizzle). Only LDS use: per-wave P round-trip for the MFMA A-fragment layout.
__global__ __launch_bounds__(256, 4)
void k_attn(const unsigned short* __restrict__ qkv, const unsigned short* __restrict__ vt,
            unsigned short* __restrict__ y) {
    __shared__ unsigned short Ps[4][16][72];
    // XCD-chunked swizzle: 1536 blocks, 192/XCD = 12 heads * 16 q-tiles -> KV slice 3MB < 4MB L2
    const int p = blockIdx.x;
    const int v = (p & 7) * 192 + (p >> 3);
    const int bh = v >> 4;
    const int qt = 15 - (v & 15);            // heavy q-tiles first
    const int b = bh / 12, h = bh % 12;
    const int q0 = qt * 64;
    const int t = threadIdx.x, w = t >> 6, l = t & 63, lr = l & 15, lg = l >> 4;
    const int qw0 = q0 + w * 16;

    const unsigned short* qbase = qkv + (size_t)b * 1024 * 2304 + h * 64;
    const unsigned short* kbase = qbase + 768;
    const unsigned short* vbase = vt + (size_t)bh * 64 * 1024;

    // Q fragments direct from global: A-frag = Q[qw0+lr][lg*8 + j]
    short8 qf0 = *(const short8*)&qbase[(size_t)(qw0 + lr) * 2304 + lg * 8];
    short8 qf1 = *(const short8*)&qbase[(size_t)(qw0 + lr) * 2304 + 32 + lg * 8];

    float m_st[4], l_st[4];
    f32x4 o_acc[4];
#pragma unroll
    for (int r = 0; r < 4; ++r) { m_st[r] = -1e30f; l_st[r] = 0.0f; }
#pragma unroll
    for (int df = 0; df < 4; ++df)
#pragma unroll
        for (int r = 0; r < 4; ++r) o_acc[df][r] = 0.0f;

    for (int kti = 0; kti <= qt; ++kti) {
        const int kt = kti * 64;
        // S[16q x 64k] = Q K^T : 8 MFMAs, K fragments direct from global
        f32x4 s[4];
#pragma unroll
        for (int nf = 0; nf < 4; ++nf) {
            const unsigned short* krow = &kbase[(size_t)(kt + nf * 16 + lr) * 2304];
            short8 kf0 = *(const short8*)&krow[lg * 8];
            short8 kf1 = *(const short8*)&krow[32 + lg * 8];
            f32x4 z;
#pragma unroll
            for (int r = 0; r < 4; ++r) z[r] = 0.0f;
            z = __builtin_amdgcn_mfma_f32_16x16x32_bf16(qf0, kf0, z, 0, 0, 0);
            z = __builtin_amdgcn_mfma_f32_16x16x32_bf16(qf1, kf1, z, 0, 0, 0);
            s[nf] = z;
        }
        // scale + causal mask (only the diagonal tile needs masking)
        const bool mask = (kti == qt);
        float sv[4][4];
#pragma unroll
        for (int nf = 0; nf < 4; ++nf) {
            int col = kt + nf * 16 + lr;
#pragma unroll
            for (int r = 0; r < 4; ++r) {
                float xv = s[nf][r] * 0.125f;
                sv[nf][r] = (!mask || col <= qw0 + lg * 4 + r) ? xv : -1e30f;
            }
        }
        // online softmax: rows live on 16-lane groups (same lg, lr = k-col)
#pragma unroll
        for (int r = 0; r < 4; ++r) {
            float mx = fmaxf(fmaxf(sv[0][r], sv[1][r]), fmaxf(sv[2][r], sv[3][r]));
#pragma unroll
            for (int d = 1; d < 16; d <<= 1) mx = fmaxf(mx, __shfl_xor(mx, d));
            float mn = fmaxf(m_st[r], mx);
            float alpha = __expf(m_st[r] - mn);
            m_st[r] = mn;
            float s_ = 0.0f;
#pragma unroll
            for (int nf = 0; nf < 4; ++nf) {
                float e = __expf(sv[nf][r] - mn);
                sv[nf][r] = e;
                s_ += e;
            }
#pragma unroll
            for (int d = 1; d < 16; d <<= 1) s_ += __shfl_xor(s_, d);
            l_st[r] = l_st[r] * alpha + s_;
#pragma unroll
            for (int df = 0; df < 4; ++df) o_acc[df][r] *= alpha;
        }
        // P -> per-wave LDS -> A-fragment layout (no cross-wave sharing, no barrier)
#pragma unroll
        for (int nf = 0; nf < 4; ++nf)
#pragma unroll
            for (int r = 0; r < 4; ++r)
                Ps[w][lg * 4 + r][nf * 16 + lr] = f2bf(sv[nf][r]);
        short8 pf0 = *(const short8*)&Ps[w][lr][lg * 8];
        short8 pf1 = *(const short8*)&Ps[w][lr][32 + lg * 8];
        // O += P V : V^T fragments direct from global (pre-transposed vt)
#pragma unroll
        for (int df = 0; df < 4; ++df) {
            const unsigned short* vrow = &vbase[(size_t)(df * 16 + lr) * 1024 + kt];
            short8 vf0 = *(const short8*)&vrow[lg * 8];
            short8 vf1 = *(const short8*)&vrow[32 + lg * 8];
            o_acc[df] = __builtin_amdgcn_mfma_f32_16x16x32_bf16(pf0, vf0, o_acc[df], 0, 0, 0);
            o_acc[df] = __builtin_amdgcn_mfma_f32_16x16x32_bf16(pf1, vf1, o_acc[df], 0, 0, 0);
        }
    }

#pragma unroll
    for (int r = 0; r < 4; ++r) {
        float inv = 1.0f / l_st[r];
        int row = qw0 + lg * 4 + r;
#pragma unroll
        for (int df = 0; df < 4; ++df)
            y[((size_t)b * 1024 + row) * 768 + h * 64 + df * 16 + lr] = f2bf(o_acc[df][r] * inv);
    }
}

extern "C" void kernel_launch(void* const* d_in, const int* in_sizes, int n_in,
                              void* d_out, int out_size, void* d_ws, size_t ws_size,
                              hipStream_t stream) {
    const float* x  = (const float*)d_in[0];
    const float* Wa = (const float*)d_in[1];
    const float* ba = (const float*)d_in[2];
    const float* Wp = (const float*)d_in[3];
    const float* bp = (const float*)d_in[4];
    float* out = (float*)d_out;

    char* ws = (char*)d_ws;
    unsigned short* qkv = (unsigned short*)ws;                          // 8192*2304*2 = 37,748,736
    unsigned short* xb  = (unsigned short*)(ws + 37748736);             // 8192*768*2  = 12,582,912
    unsigned short* WaT = (unsigned short*)(ws + 37748736 + 12582912);  // 2304*768*2  =  3,538,944
    unsigned short* y   = xb;    // reuse: xb dead after gemm1
    unsigned short* WpT = WaT;   // reuse: WaT dead after gemm1
    unsigned short* vtb = (unsigned short*)d_out;  // V^T scratch lives in d_out (12.6MB < 25.2MB),
                                                   // fully overwritten by gemm2 afterwards

    // 1) x fp32 -> bf16
    k_f32_to_bf16<<<6144, 256, 0, stream>>>(x, xb, 1572864);
    // 2) W_attn [768][2304] -> bf16 [2304][768]
    k_transpose_f32_bf16<<<dim3(72, 24), 256, 0, stream>>>(Wa, WaT, 768, 2304);
    // 3) qkv = xb @ WaT^T + b_attn   (bf16 out)
    k_gemm_bt<false><<<dim3(18, 64), 256, 0, stream>>>(xb, WaT, ba, qkv, 8192, 2304, 768);
    // 4) V head-transpose into d_out scratch
    k_vt<<<dim3(32, 2, 96), 256, 0, stream>>>(qkv, vtb);
    // 5) causal flash attention -> y (bf16), overwrites xb region
    k_attn<<<1536, 256, 0, stream>>>(qkv, vtb, y);
    // 6) W_proj [768][768] -> bf16 transposed
    k_transpose_f32_bf16<<<dim3(24, 24), 256, 0, stream>>>(Wp, WpT, 768, 768);
    // 7) out = y @ WpT^T + b_proj    (fp32 out)
    k_gemm_bt<true><<<dim3(6, 64), 256, 0, stream>>>(y, WpT, bp, out, 8192, 768, 768);
}